// Round 7
// baseline (10617.976 us; speedup 1.0000x reference)
//
#include <hip/hip_runtime.h>
#include <math.h>

#define HH 256
#define FIN 6
#define TT 4096
#define BB 32
#define TH 0.05f

// d_ws layout: [0,3MB) feats fp32; [EXO,+32KB) dh exchange; [FLO,+8KB) flags
#define EXO (3 * 1024 * 1024)
#define FLO (EXO + 32 * 1024)

typedef _Float16 h2 __attribute__((ext_vector_type(2)));
typedef int iv64 __attribute__((ext_vector_type(64)));   // 64 regs = 64 packed h2 = 128 halfs
struct H8 { h2 a, b, c, d; };   // 16 B = 8 halfs

__device__ __forceinline__ int packh2(float a, float b) {
    h2 v = { (_Float16)a, (_Float16)b };
    return __builtin_bit_cast(int, v);
}
__device__ __forceinline__ h2 toh2(int x) { return __builtin_bit_cast(h2, x); }
__device__ __forceinline__ float fdot2(h2 a, h2 b, float c) {
    return __builtin_amdgcn_fdot2(a, b, c, false);
}
__device__ __forceinline__ float hswish(float v) {
    float c = fminf(fmaxf(v + 3.0f, 0.0f), 6.0f);
    return v * c * (1.0f / 6.0f);
}
__device__ __forceinline__ float fexp2(float x) { return __builtin_amdgcn_exp2f(x); }
__device__ __forceinline__ float frcp(float x)  { return __builtin_amdgcn_rcpf(x); }
__device__ __forceinline__ float sigm(float x)  { return frcp(1.0f + fexp2(-1.44269504f * x)); }
__device__ __forceinline__ float tanhf_fast(float x) {
    float ax = fabsf(x);
    float e = fexp2(2.88539008f * ax);
    float t = 1.0f - 2.0f * frcp(e + 1.0f);
    return copysignf(t, x);
}

// Kernel 1: feats into ws, conv skip into d_out, zero the sync flags.
__global__ __launch_bounds__(256) void k_prep(
        const float* __restrict__ x, const float* __restrict__ Wc1,
        const float* __restrict__ Wc2, float* __restrict__ feats,
        float* __restrict__ out, char* __restrict__ ws) {
    int idx = blockIdx.x * 256 + threadIdx.x;   // b*T + t
    if (idx < 2048) ((int*)(ws + FLO))[idx] = 0;    // flags region (8 KB)
    if (idx >= BB * TT) return;
    int b = idx >> 12;
    int t = idx & (TT - 1);
    const float* xb = x + (size_t)b * TT * 2;
    float i0 = xb[t * 2 + 0], q0 = xb[t * 2 + 1];
    float ip = (t > 0) ? xb[(t - 1) * 2 + 0] : 0.0f;
    float qp = (t > 0) ? xb[(t - 1) * 2 + 1] : 0.0f;
    float amp2 = i0 * i0 + q0 * q0;
    float amp  = sqrtf(fmaxf(amp2, 1e-12f));
    float amp3 = amp * amp2;
    float* f = feats + (size_t)idx * 6;
    f[0] = i0; f[1] = q0; f[2] = amp; f[3] = amp3; f[4] = ip; f[5] = qp;

    float c1[3];
#pragma unroll
    for (int m = 0; m < 3; m++) {
        float acc = 0.0f;
#pragma unroll
        for (int k = 0; k < 3; k++) {
            int tt = t + (k - 1) * 16;
            if (tt >= 0 && tt < TT) {
                acc += Wc1[m * 6 + 0 * 3 + k] * xb[tt * 2 + 0];
                acc += Wc1[m * 6 + 1 * 3 + k] * xb[tt * 2 + 1];
            }
        }
        c1[m] = hswish(acc);
    }
#pragma unroll
    for (int o = 0; o < 2; o++) {
        float acc = Wc2[o * 3 + 0] * c1[0] + Wc2[o * 3 + 1] * c1[1] + Wc2[o * 3 + 2] * c1[2];
        out[(size_t)idx * 2 + o] = hswish(acc);
    }
}

__device__ __forceinline__ iv64 load_pack64(const float* rowptr) {
    iv64 v{};
    const float4* p = (const float4*)rowptr;
#pragma unroll
    for (int c = 0; c < 32; c++) {
        float4 t = p[c];
        v[2 * c]     = packh2(t.x, t.y);
        v[2 * c + 1] = packh2(t.z, t.w);
    }
    return v;
}

// Kernel 2: delta-GRU, TWO blocks per batch (64 blocks, 256 threads each).
// Block (b, sub): owns h rows [sub*128, sub*128+128). Thread layout (R3-proven):
// wave wv, lane; half = lane>>5 picks K-half, j = wv*32+(lane&31) in [0,128).
// Thread holds 3 gate-rows (r,z,n for hrow=sub*128+j) x half-K as packed fp16
// in iv64 vectors: 192 VGPRs. Fits the 256 budget -> no structural spill.
// Per step the pair exchanges 128 dh (256 B) via L2 + release/acquire flags.
__global__ __launch_bounds__(256, 1) void k_gru(
        const float* __restrict__ feats, const float* __restrict__ Wx,
        const float* __restrict__ Wh, const float* __restrict__ Wo,
        float* __restrict__ out, char* __restrict__ ws) {
    __shared__ float s_out[TT * 2];                    // 32 KB partial-output accumulator
    __shared__ __align__(16) _Float16 s_dhh[2][HH];    // full dh (own half + partner half)
    __shared__ __align__(16) float s_dx[2][8];
    __shared__ float s_feat[2][128 * FIN];

    const int tid  = threadIdx.x;
    const int bb   = blockIdx.x;
    const int b    = bb & 31;
    const int sub  = bb >> 5;
    const int wv   = tid >> 6;
    const int lane = tid & 63;
    const int half = lane >> 5;
    const int jl   = lane & 31;
    const int j    = wv * 32 + jl;        // 0..127 local h index
    const int hrow = sub * 128 + j;       // 0..255 global h row
    const int k0   = half * 128;          // K-half offset

    const float* fb = feats + (size_t)b * TT * FIN;
    ushort* ex = (ushort*)(ws + EXO);
    int* flags = (int*)(ws + FLO);
    ushort* ex_out = ex + (size_t)((b * 2 + sub) * 2) * 128;         // + slot*128
    const ushort* ex_in = ex + (size_t)((b * 2 + (1 - sub)) * 2) * 128;
    int* myflag = flags + (b * 2 + sub) * 32;        // 128-B stride
    int* pflag  = flags + (b * 2 + (1 - sub)) * 32;

    for (int i = tid; i < TT * 2; i += 256) s_out[i] = 0.0f;
    for (int i = tid; i < 128 * FIN; i += 256) s_feat[0][i] = fb[i];

    // persistent weights: 3 gate rows, this thread's K-half (3 x 64 regs)
    const iv64 wrv = load_pack64(Wh + (size_t)(0 * HH + hrow) * HH + k0);
    const iv64 wzv = load_pack64(Wh + (size_t)(1 * HH + hrow) * HH + k0);
    const iv64 wnv = load_pack64(Wh + (size_t)(2 * HH + hrow) * HH + k0);

    // fp32 Wx slice: this half covers features [half*3, half*3+3)
    const int f0 = half * 3;
    float wxr[3], wxz[3], wxn[3];
#pragma unroll
    for (int i = 0; i < 3; i++) {
        wxr[i] = Wx[(size_t)(0 * HH + hrow) * FIN + f0 + i];
        wxz[i] = Wx[(size_t)(1 * HH + hrow) * FIN + f0 + i];
        wxn[i] = Wx[(size_t)(2 * HH + hrow) * FIN + f0 + i];
    }
    const float woc = Wo[half * HH + hrow];   // half 0 -> ch0, half 1 -> ch1

    float h = 0.0f, hp = 0.0f, dmr = 0.0f, dmz = 0.0f, dmn = 0.0f, dmnh = 0.0f;
    float xp = 0.0f, curf = 0.0f;
    if (tid < FIN) curf = fb[tid];

    __syncthreads();

#pragma unroll 1
    for (int t = 0; t < TT; t++) {
        const int tb = t & 1;

        if ((t & 127) == 64 && t + 64 < TT) {
            const int w = (t >> 7) + 1;
            for (int i = tid; i < 128 * FIN; i += 256)
                s_feat[w & 1][i] = fb[(size_t)w * 128 * FIN + i];
        }

        // ---- phase A: thresholded deltas; publish own dh half ----
        {
            float dh = h - hp;
            bool keep = fabsf(dh) >= TH;
            float dhv = keep ? dh : 0.0f;
            if (keep) hp = h;
            if (half == 0) {
                _Float16 dq = (_Float16)dhv;
                s_dhh[tb][hrow] = dq;
                ex_out[tb * 128 + j] = __builtin_bit_cast(ushort, dq);
            }
        }
        if (tid < FIN) {
            float dx = curf - xp;
            bool keep = fabsf(dx) >= TH;
            s_dx[tb][tid] = keep ? dx : 0.0f;
            if (keep) xp = curf;
        }
        __syncthreads();   // compiler-emitted vmcnt(0) drain -> exchange stores in L2

        if (tid == 192)
            __hip_atomic_store(myflag, t + 1, __ATOMIC_RELEASE, __HIP_MEMORY_SCOPE_AGENT);
        if (tid < 16) {
            while (__hip_atomic_load(pflag, __ATOMIC_ACQUIRE, __HIP_MEMORY_SCOPE_AGENT) < t + 1) {}
            uint4 v = ((const uint4*)(ex_in + tb * 128))[tid];
            ((uint4*)&s_dhh[tb][(1 - sub) * 128])[tid] = v;
        }
        __syncthreads();   // partner dh visible in LDS

        // ---- phase B: half mac_x (fp32) + half-K fp16 dots over full dh ----
        float ar, az, anx, anh = 0.0f;
        {
            const float* dxp = s_dx[tb];
            float d0 = dxp[f0 + 0], d1 = dxp[f0 + 1], d2 = dxp[f0 + 2];
            ar  = d0 * wxr[0]; ar  = fmaf(d1, wxr[1], ar);  ar  = fmaf(d2, wxr[2], ar);
            az  = d0 * wxz[0]; az  = fmaf(d1, wxz[1], az);  az  = fmaf(d2, wxz[2], az);
            anx = d0 * wxn[0]; anx = fmaf(d1, wxn[1], anx); anx = fmaf(d2, wxn[2], anx);
        }
        {
            const H8* dp = (const H8*)s_dhh[tb] + half * 16;
#pragma unroll
            for (int c = 0; c < 16; c++) {
                H8 d = dp[c];
                ar  = fdot2(d.a, toh2(wrv[4 * c + 0]), ar);
                az  = fdot2(d.a, toh2(wzv[4 * c + 0]), az);
                anh = fdot2(d.a, toh2(wnv[4 * c + 0]), anh);
                ar  = fdot2(d.b, toh2(wrv[4 * c + 1]), ar);
                az  = fdot2(d.b, toh2(wzv[4 * c + 1]), az);
                anh = fdot2(d.b, toh2(wnv[4 * c + 1]), anh);
                ar  = fdot2(d.c, toh2(wrv[4 * c + 2]), ar);
                az  = fdot2(d.c, toh2(wzv[4 * c + 2]), az);
                anh = fdot2(d.c, toh2(wnv[4 * c + 2]), anh);
                ar  = fdot2(d.d, toh2(wrv[4 * c + 3]), ar);
                az  = fdot2(d.d, toh2(wzv[4 * c + 3]), az);
                anh = fdot2(d.d, toh2(wnv[4 * c + 3]), anh);
            }
        }
        // combine K-halves: identical full sums land in both halves
        ar  += __shfl_xor(ar, 32, 64);
        az  += __shfl_xor(az, 32, 64);
        anx += __shfl_xor(anx, 32, 64);
        anh += __shfl_xor(anh, 32, 64);

        dmr  += ar;
        dmz  += az;
        dmn  += anx;
        dmnh += anh;

        // ---- phase C: gates + h update (thread-local, redundant in halves) ----
        {
            float r = sigm(dmr);
            float z = sigm(dmz);
            float nn = tanhf_fast(dmn + r * dmnh);
            h = (1.0f - z) * nn + z * h;
        }

        // ---- output partial for this block's 128 rows: half -> channel ----
        {
            float p = h * woc;
            p += __shfl_xor(p, 1, 64);
            p += __shfl_xor(p, 2, 64);
            p += __shfl_xor(p, 4, 64);
            p += __shfl_xor(p, 8, 64);
            p += __shfl_xor(p, 16, 64);
            if (jl == 0) atomicAdd(&s_out[2 * t + half], p);
        }

        if (tid < FIN && t + 1 < TT) {
            const int tn = t + 1;
            curf = s_feat[(tn >> 7) & 1][(tn & 127) * FIN + tid];
        }
    }

    __syncthreads();
    const size_t outbase = (size_t)b * TT * 2;
    for (int i = tid; i < TT * 2; i += 256)
        atomicAdd(&out[outbase + i], s_out[i]);   // onto skip pre-written by k_prep
}

extern "C" void kernel_launch(void* const* d_in, const int* in_sizes, int n_in,
                              void* d_out, int out_size, void* d_ws, size_t ws_size,
                              hipStream_t stream) {
    const float* x   = (const float*)d_in[0];
    const float* Wx  = (const float*)d_in[1];
    const float* Wh  = (const float*)d_in[2];
    const float* Wo  = (const float*)d_in[3];
    const float* Wc1 = (const float*)d_in[4];
    const float* Wc2 = (const float*)d_in[5];
    float* out = (float*)d_out;
    float* feats = (float*)d_ws;
    char* ws = (char*)d_ws;

    k_prep<<<(BB * TT + 255) / 256, 256, 0, stream>>>(x, Wc1, Wc2, feats, out, ws);
    k_gru<<<64, 256, 0, stream>>>(feats, Wx, Wh, Wo, out, ws);
}

// Round 8
// 9600.182 us; speedup vs baseline: 1.1060x; 1.1060x over previous
//
#include <hip/hip_runtime.h>
#include <math.h>

#define HH 256
#define FIN 6
#define TT 4096
#define BB 32
#define TH 0.05f
#define ZB0 13                       // first z-gate chunk served from L2 stream
#define ZNCH 19                      // number of z L2 chunks (13..31)
#define ZBO (BB * TT * FIN * 4)      // zbuf offset in ws (after feats) = 3145728

typedef _Float16 h2 __attribute__((ext_vector_type(2)));
typedef int iv64 __attribute__((ext_vector_type(64)));   // 64 regs = 128 halfs

__device__ __forceinline__ int packh2(float a, float b) {
    h2 v = { (_Float16)a, (_Float16)b };
    return __builtin_bit_cast(int, v);
}
__device__ __forceinline__ h2 toh2(int x) { return __builtin_bit_cast(h2, x); }
__device__ __forceinline__ float fdot2(h2 a, h2 b, float c) {
    return __builtin_amdgcn_fdot2(a, b, c, false);
}
__device__ __forceinline__ float hswish(float v) {
    float c = fminf(fmaxf(v + 3.0f, 0.0f), 6.0f);
    return v * c * (1.0f / 6.0f);
}
__device__ __forceinline__ float fexp2(float x) { return __builtin_amdgcn_exp2f(x); }
__device__ __forceinline__ float frcp(float x)  { return __builtin_amdgcn_rcpf(x); }
__device__ __forceinline__ float sigm(float x)  { return frcp(1.0f + fexp2(-1.44269504f * x)); }
__device__ __forceinline__ float tanhf_fast(float x) {
    float ax = fabsf(x);
    float e = fexp2(2.88539008f * ax);
    float t = 1.0f - 2.0f * frcp(e + 1.0f);
    return copysignf(t, x);
}

// 64-lane sum via DPP (VALU pipe only; keeps the DS pipe free). Result uniform.
__device__ __forceinline__ float wave_sum(float x) {
    union fi { float f; int i; };
    fi v; v.f = x; fi t;
    t.i = __builtin_amdgcn_update_dpp(0, v.i, 0x111, 0xf, 0xf, false); v.f += t.f; // row_shr:1
    t.i = __builtin_amdgcn_update_dpp(0, v.i, 0x112, 0xf, 0xf, false); v.f += t.f; // row_shr:2
    t.i = __builtin_amdgcn_update_dpp(0, v.i, 0x114, 0xf, 0xf, false); v.f += t.f; // row_shr:4
    t.i = __builtin_amdgcn_update_dpp(0, v.i, 0x118, 0xf, 0xf, false); v.f += t.f; // row_shr:8
    t.i = __builtin_amdgcn_update_dpp(0, v.i, 0x142, 0xa, 0xf, false); v.f += t.f; // row_bcast:15
    t.i = __builtin_amdgcn_update_dpp(0, v.i, 0x143, 0xc, 0xf, false); v.f += t.f; // row_bcast:31
    fi r; r.i = __builtin_amdgcn_readlane(v.i, 63);
    return r.f;
}

// Kernel 1: feats into ws, conv skip into d_out, pack z-gate L2-tier weights.
__global__ __launch_bounds__(256) void k_prep(
        const float* __restrict__ x, const float* __restrict__ Wh,
        const float* __restrict__ Wc1, const float* __restrict__ Wc2,
        float* __restrict__ feats, float* __restrict__ out,
        char* __restrict__ ws) {
    int idx = blockIdx.x * 256 + threadIdx.x;   // b*T + t

    // pack z-gate K[104,256) as fp16 int4 chunks: zbuf[c*256 + row]
    if (idx < ZNCH * 256) {
        int c = idx >> 8, row = idx & 255;
        const float4* p = (const float4*)(Wh + (size_t)(HH + row) * HH + (104 + 8 * c));
        float4 a = p[0], b4 = p[1];
        int4 w;
        w.x = packh2(a.x, a.y);  w.y = packh2(a.z, a.w);
        w.z = packh2(b4.x, b4.y); w.w = packh2(b4.z, b4.w);
        ((int4*)(ws + ZBO))[idx] = w;
    }

    if (idx >= BB * TT) return;
    int b = idx >> 12;
    int t = idx & (TT - 1);
    const float* xb = x + (size_t)b * TT * 2;
    float i0 = xb[t * 2 + 0], q0 = xb[t * 2 + 1];
    float ip = (t > 0) ? xb[(t - 1) * 2 + 0] : 0.0f;
    float qp = (t > 0) ? xb[(t - 1) * 2 + 1] : 0.0f;
    float amp2 = i0 * i0 + q0 * q0;
    float amp  = sqrtf(fmaxf(amp2, 1e-12f));
    float amp3 = amp * amp2;
    float* f = feats + (size_t)idx * 6;
    f[0] = i0; f[1] = q0; f[2] = amp; f[3] = amp3; f[4] = ip; f[5] = qp;

    float c1[3];
#pragma unroll
    for (int m = 0; m < 3; m++) {
        float acc = 0.0f;
#pragma unroll
        for (int k = 0; k < 3; k++) {
            int tt = t + (k - 1) * 16;
            if (tt >= 0 && tt < TT) {
                acc += Wc1[m * 6 + 0 * 3 + k] * xb[tt * 2 + 0];
                acc += Wc1[m * 6 + 1 * 3 + k] * xb[tt * 2 + 1];
            }
        }
        c1[m] = hswish(acc);
    }
#pragma unroll
    for (int o = 0; o < 2; o++) {
        float acc = Wc2[o * 3 + 0] * c1[0] + Wc2[o * 3 + 1] * c1[1] + Wc2[o * 3 + 2] * c1[2];
        out[(size_t)idx * 2 + o] = hswish(acc);
    }
}

__device__ __forceinline__ iv64 load_pack64(const float* rowptr) {
    iv64 v{};
    const float4* p = (const float4*)rowptr;
#pragma unroll
    for (int c = 0; c < 32; c++) {
        float4 t = p[c];
        v[2 * c]     = packh2(t.x, t.y);
        v[2 * c + 1] = packh2(t.z, t.w);
    }
    return v;
}

// Kernel 2: delta-GRU, one block (1 CU) per batch, 256 threads.
// Thread tid owns gate-rows {tid, 256+tid, 512+tid}, full K=256.
// 3-tier weight residency (384 KB fp16 total per CU):
//   regs (192/thread = 196 KB): r K[0,256) (2 x iv64) + n K[0,128) (iv64)
//   LDS  (119 KB):   n K[128,256) + z K[0,104), [chunk][tid] int4-interleaved
//   L2 stream (78 KB/step): z K[104,256) from pre-packed zbuf (L2-resident)
// dh broadcast via one strided ds_read_b128 + v_readlane (VALU, not DS pipe).
__global__ __launch_bounds__(256, 1) void k_gru(
        const float* __restrict__ feats, const float* __restrict__ Wx,
        const float* __restrict__ Wh, const float* __restrict__ Wo,
        float* __restrict__ out, char* __restrict__ ws) {
    __shared__ int4 s_wn[16 * 256];                    // 64 KB: n-gate K[128,256)
    __shared__ int4 s_wz[13 * 256];                    // 52 KB: z-gate K[0,104)
    __shared__ float s_out[TT * 2];                    // 32 KB output accumulator
    __shared__ float s_feat[2][128 * FIN];             // 6 KB feat windows
    __shared__ __align__(16) _Float16 s_dhh[2][HH];    // 1 KB dh double-buffer
    __shared__ __align__(16) float s_dx[2][8];

    const int tid  = threadIdx.x;
    const int lane = tid & 63;
    const int b    = blockIdx.x;
    const float* fb = feats + (size_t)b * TT * FIN;
    const int4* zl2 = (const int4*)(ws + ZBO) + tid;

    for (int i = tid; i < TT * 2; i += 256) s_out[i] = 0.0f;
#pragma unroll
    for (int k = 0; k < 3; k++) s_feat[0][tid + k * 256] = fb[tid + k * 256];

    const float* rowr = Wh + (size_t)(0 * HH + tid) * HH;
    const float* rowz = Wh + (size_t)(1 * HH + tid) * HH;
    const float* rown = Wh + (size_t)(2 * HH + tid) * HH;

    // register tier
    iv64 wr0 = load_pack64(rowr);          // r K[0,128)
    iv64 wr1 = load_pack64(rowr + 128);    // r K[128,256)
    iv64 wn0 = load_pack64(rown);          // n K[0,128)

    // LDS tier: n K[128,256) chunks 0..15, z K[0,104) chunks 0..12
#pragma unroll
    for (int c = 0; c < 16; c++) {
        const float4* p = (const float4*)(rown + 128 + 8 * c);
        float4 a = p[0], d4 = p[1];
        int4 w; w.x = packh2(a.x, a.y); w.y = packh2(a.z, a.w);
        w.z = packh2(d4.x, d4.y); w.w = packh2(d4.z, d4.w);
        s_wn[c * 256 + tid] = w;
    }
#pragma unroll
    for (int c = 0; c < 13; c++) {
        const float4* p = (const float4*)(rowz + 8 * c);
        float4 a = p[0], d4 = p[1];
        int4 w; w.x = packh2(a.x, a.y); w.y = packh2(a.z, a.w);
        w.z = packh2(d4.x, d4.y); w.w = packh2(d4.z, d4.w);
        s_wz[c * 256 + tid] = w;
    }

    float wxr[FIN], wxz[FIN], wxn[FIN];
#pragma unroll
    for (int f = 0; f < FIN; f++) {
        wxr[f] = Wx[(size_t)(0 * HH + tid) * FIN + f];
        wxz[f] = Wx[(size_t)(1 * HH + tid) * FIN + f];
        wxn[f] = Wx[(size_t)(2 * HH + tid) * FIN + f];
    }
    const float wo0 = Wo[tid], wo1 = Wo[HH + tid];

    float h = 0.0f, hp = 0.0f, dmr = 0.0f, dmz = 0.0f, dmn = 0.0f, dmnh = 0.0f;
    float xp = 0.0f, curf = 0.0f;
    if (tid < FIN) curf = fb[tid];

    __syncthreads();

#pragma unroll 1
    for (int t = 0; t < TT; t++) {
        const int tb = t & 1;

        if ((t & 127) == 64 && t + 64 < TT) {
            const int w = (t >> 7) + 1;
#pragma unroll
            for (int k = 0; k < 3; k++)
                s_feat[w & 1][tid + k * 256] = fb[(size_t)w * 128 * FIN + tid + k * 256];
        }

        // ---- phase A: thresholded deltas ----
        {
            float dh = h - hp;
            bool keep = fabsf(dh) >= TH;
            s_dhh[tb][tid] = (_Float16)(keep ? dh : 0.0f);
            if (keep) hp = h;
        }
        if (tid < FIN) {
            float dx = curf - xp;
            bool keep = fabsf(dx) >= TH;
            s_dx[tb][tid] = keep ? dx : 0.0f;
            if (keep) xp = curf;
        }
        __syncthreads();

        // ---- phase B: mac_x (fp32) ----
        float mxr = dmr, mxz = dmz, mxn = dmn;
        {
            const float4* dx4 = (const float4*)s_dx[tb];
            float4 da = dx4[0], db = dx4[1];
            mxr = fmaf(da.x, wxr[0], mxr); mxz = fmaf(da.x, wxz[0], mxz); mxn = fmaf(da.x, wxn[0], mxn);
            mxr = fmaf(da.y, wxr[1], mxr); mxz = fmaf(da.y, wxz[1], mxz); mxn = fmaf(da.y, wxn[1], mxn);
            mxr = fmaf(da.z, wxr[2], mxr); mxz = fmaf(da.z, wxz[2], mxz); mxn = fmaf(da.z, wxn[2], mxn);
            mxr = fmaf(da.w, wxr[3], mxr); mxz = fmaf(da.w, wxz[3], mxz); mxn = fmaf(da.w, wxn[3], mxn);
            mxr = fmaf(db.x, wxr[4], mxr); mxz = fmaf(db.x, wxz[4], mxz); mxn = fmaf(db.x, wxn[4], mxn);
            mxr = fmaf(db.y, wxr[5], mxr); mxz = fmaf(db.y, wxz[5], mxz); mxn = fmaf(db.y, wxn[5], mxn);
        }

        // ---- dh dot: one strided b128 + readlane broadcast; 3-tier weights ----
        float ar = 0.0f, az = 0.0f, an = 0.0f;
        int4 vdh = ((const int4*)s_dhh[tb])[lane & 31];   // lane c holds dh chunk c
#pragma unroll
        for (int c = 0; c < 32; c++) {
            h2 e0 = toh2(__builtin_amdgcn_readlane(vdh.x, c));
            h2 e1 = toh2(__builtin_amdgcn_readlane(vdh.y, c));
            h2 e2 = toh2(__builtin_amdgcn_readlane(vdh.z, c));
            h2 e3 = toh2(__builtin_amdgcn_readlane(vdh.w, c));
            if (c < 16) {
                ar = fdot2(e0, toh2(wr0[4 * c + 0]), ar);
                ar = fdot2(e1, toh2(wr0[4 * c + 1]), ar);
                ar = fdot2(e2, toh2(wr0[4 * c + 2]), ar);
                ar = fdot2(e3, toh2(wr0[4 * c + 3]), ar);
                an = fdot2(e0, toh2(wn0[4 * c + 0]), an);
                an = fdot2(e1, toh2(wn0[4 * c + 1]), an);
                an = fdot2(e2, toh2(wn0[4 * c + 2]), an);
                an = fdot2(e3, toh2(wn0[4 * c + 3]), an);
            } else {
                ar = fdot2(e0, toh2(wr1[4 * (c - 16) + 0]), ar);
                ar = fdot2(e1, toh2(wr1[4 * (c - 16) + 1]), ar);
                ar = fdot2(e2, toh2(wr1[4 * (c - 16) + 2]), ar);
                ar = fdot2(e3, toh2(wr1[4 * (c - 16) + 3]), ar);
                int4 wn = s_wn[(c - 16) * 256 + tid];
                an = fdot2(e0, toh2(wn.x), an);
                an = fdot2(e1, toh2(wn.y), an);
                an = fdot2(e2, toh2(wn.z), an);
                an = fdot2(e3, toh2(wn.w), an);
            }
            int4 wz = (c < ZB0) ? s_wz[c * 256 + tid] : zl2[(c - ZB0) * 256];
            az = fdot2(e0, toh2(wz.x), az);
            az = fdot2(e1, toh2(wz.y), az);
            az = fdot2(e2, toh2(wz.z), az);
            az = fdot2(e3, toh2(wz.w), az);
        }

        dmr = mxr + ar;
        dmz = mxz + az;
        dmn = mxn;
        dmnh += an;

        // ---- phase C: gates + h update ----
        {
            float r = sigm(dmr);
            float z = sigm(dmz);
            float nn = tanhf_fast(dmn + r * dmnh);
            h = (1.0f - z) * nn + z * h;
        }

        // ---- output: DPP wave-sum (VALU) + LDS atomic ----
        {
            float p0 = wave_sum(h * wo0);
            float p1 = wave_sum(h * wo1);
            if (lane == 0) {
                atomicAdd(&s_out[2 * t + 0], p0);
                atomicAdd(&s_out[2 * t + 1], p1);
            }
        }

        if (tid < FIN && t + 1 < TT) {
            const int tn = t + 1;
            curf = s_feat[(tn >> 7) & 1][(tn & 127) * FIN + tid];
        }
    }

    __syncthreads();
    const size_t outbase = (size_t)b * TT * 2;
    for (int i = tid; i < TT * 2; i += 256) out[outbase + i] += s_out[i];
}

extern "C" void kernel_launch(void* const* d_in, const int* in_sizes, int n_in,
                              void* d_out, int out_size, void* d_ws, size_t ws_size,
                              hipStream_t stream) {
    const float* x   = (const float*)d_in[0];
    const float* Wx  = (const float*)d_in[1];
    const float* Wh  = (const float*)d_in[2];
    const float* Wo  = (const float*)d_in[3];
    const float* Wc1 = (const float*)d_in[4];
    const float* Wc2 = (const float*)d_in[5];
    float* out = (float*)d_out;
    float* feats = (float*)d_ws;              // [0, 3 MB): feats; [ZBO, +78 KB): z L2 tier
    char* ws = (char*)d_ws;

    k_prep<<<(BB * TT + 255) / 256, 256, 0, stream>>>(x, Wh, Wc1, Wc2, feats, out, ws);
    k_gru<<<BB, 256, 0, stream>>>(feats, Wx, Wh, Wo, out, ws);
}